// Round 6
// baseline (232.101 us; speedup 1.0000x reference)
//
#include <hip/hip_runtime.h>
#include <float.h>
#include <math.h>

#define EPS 1e-5f
constexpr int B = 4, C = 3, N = 4096, E = 256;
constexpr int KNN = 15;            // 15 neighbors kept (top-16 minus rank 0)
constexpr int BN_ = B * N;         // 16384
constexpr int P = 8;               // points per block in fused kernel
constexpr int SR  = 264;           // hh_bf row stride (ushorts)
constexpr int SRF = 520;           // feat_bf row stride (ushorts)

typedef short bf8 __attribute__((ext_vector_type(8)));   // 8 bf16 in 4 VGPRs
typedef float f4  __attribute__((ext_vector_type(4)));

static __device__ __forceinline__ unsigned short f2bf(float f) {
    union { float f; unsigned int u; } v; v.f = f;
    unsigned int r = v.u + 0x7FFFu + ((v.u >> 16) & 1u);   // RTNE
    return (unsigned short)(r >> 16);
}
// packed 2xbf16 convert (RNE), lo = a, hi = b
static __device__ __forceinline__ unsigned int pkbf(float a, float b) {
    unsigned int r;
    asm("v_cvt_pk_bf16_f32 %0, %1, %2" : "=v"(r) : "v"(a), "v"(b));
    return r;
}
static __device__ __forceinline__ bf8 ld_bf8(const unsigned short* p) {
    return *(const bf8*)p;
}
// tanh-GELU: max |err| vs exact erf-gelu ~3e-4 (<< bf16 rounding).
static __device__ __forceinline__ float gelu_t(float v) {
    float z = v * fmaf(v * v, 0.07135482f, 1.59576912f);   // z = 2u
    float r = __builtin_amdgcn_rcpf(1.f + __expf(z));
    return fmaf(-v, r, v);
}

// DPP-based wave64 max: row_shr 1/2/4/8 then row_bcast 15/31; result in lane 63,
// broadcast via readlane. Pure-VALU latency (~5cy/step) vs ds_swizzle (~30cy/step).
// dpp_ctrl must be an ICE -> template parameter.
template <int CTRL>
static __device__ __forceinline__ float dppmax(float x) {
    int xi = __float_as_int(x);
    int yi = __builtin_amdgcn_update_dpp(xi, xi, CTRL, 0xF, 0xF, false);
    return fmaxf(x, __int_as_float(yi));
}
static __device__ __forceinline__ float wave_max_bcast(float x) {
    x = dppmax<0x111>(x);   // row_shr:1
    x = dppmax<0x112>(x);   // row_shr:2
    x = dppmax<0x114>(x);   // row_shr:4
    x = dppmax<0x118>(x);   // row_shr:8
    x = dppmax<0x142>(x);   // row_bcast:15
    x = dppmax<0x143>(x);   // row_bcast:31
    return __int_as_float(__builtin_amdgcn_readlane(__float_as_int(x), 63));
}

// ---------------- K1: per-channel mean/rstd of x over (B,N) ----------------
__global__ void bn1_stats(const float* __restrict__ x, float* __restrict__ bn1) {
    int c = blockIdx.x, t = threadIdx.x;
    float s = 0.f, ss = 0.f;
    for (int i4 = t; i4 < BN_ / 4; i4 += 256) {
        int b = i4 >> 10, n4 = i4 & 1023;
        float4 v = ((const float4*)(x + (b * C + c) * N))[n4];
        s += v.x + v.y + v.z + v.w;
        ss += v.x * v.x + v.y * v.y + v.z * v.z + v.w * v.w;
    }
    __shared__ float rs_[256], rss_[256];
    rs_[t] = s; rss_[t] = ss; __syncthreads();
    for (int w = 128; w > 0; w >>= 1) {
        if (t < w) { rs_[t] += rs_[t + w]; rss_[t] += rss_[t + w]; }
        __syncthreads();
    }
    if (t == 0) {
        float mu = rs_[0] / (float)BN_;
        float var = rss_[0] / (float)BN_ - mu * mu;
        bn1[c] = mu; bn1[3 + c] = rsqrtf(var + EPS);
    }
}

// ---------------- K2: xn4 AoS (blocks 0..63) + tile-lane-major bf16 weights ----------------
// w2b_t: chunk (ft*8+kb)*64+lane holds W2b[ft*16+(lane&15)][kb*32+(lane>>4)*8 ..+8]  (ft-stride 4096)
// wf_t : chunk (ot*16+kb)*64+lane holds Wf[ot*16+(lane&15)][kb*32+(lane>>4)*8 ..+8]  (ot-stride 8192)
__global__ void compute_xn_cvt(const float* __restrict__ x,
                               const float* __restrict__ g1,
                               const float* __restrict__ b1,
                               const float* __restrict__ bn1,
                               float4* __restrict__ xn4,
                               const float* __restrict__ W2b, const float* __restrict__ Wf,
                               unsigned short* __restrict__ w2b_t, unsigned short* __restrict__ wf_t) {
    int blk = blockIdx.x;
    if (blk < BN_ / 256) {
        int i = blk * 256 + threadIdx.x;
        int b = i >> 12, n = i & (N - 1);
        float v[3];
        #pragma unroll
        for (int c = 0; c < C; c++)
            v[c] = (x[(b * C + c) * N + n] - bn1[c]) * bn1[3 + c] * g1[c] + b1[c];
        float4 o; o.x = v[0]; o.y = v[1]; o.z = v[2];
        o.w = v[0] * v[0] + v[1] * v[1] + v[2] * v[2];
        xn4[i] = o;
        return;
    }
    int ch = (blk - BN_ / 256) * 256 + threadIdx.x;   // chunk id (8 bf16 per chunk)
    if (ch < 8192) {               // w2b: 65536 elems = 8192 chunks
        int lane = ch & 63, kb = (ch >> 6) & 7, ft16 = ch >> 9;
        int row = ft16 * 16 + (lane & 15);
        int col = kb * 32 + (lane >> 4) * 8;
        #pragma unroll
        for (int j = 0; j < 8; j++)
            w2b_t[ch * 8 + j] = f2bf(W2b[row * 256 + col + j]);
    } else {                       // wf: 131072 elems = 16384 chunks
        int c2 = ch - 8192;
        int lane = c2 & 63, kb = (c2 >> 6) & 15, ot = c2 >> 10;
        int row = ot * 16 + (lane & 15);
        int col = kb * 32 + (lane >> 4) * 8;
        #pragma unroll
        for (int j = 0; j < 8; j++)
            wf_t[c2 * 8 + j] = f2bf(Wf[row * 512 + col + j]);
    }
}

// ---------------- K3: top-16 (largest d2), one WAVE per point ----------------
// LDS-staged xb tiles (4 x 16KB chunks shared by the block's 4 waves): L2->CU
// traffic /4 vs per-wave global streaming.  Chunk loop fully unrolled so d[]
// stays register-indexed.  Wave max via DPP (latency ~30cy vs ~180cy swizzle chain).
__global__ void __launch_bounds__(256, 4) knn_kernel(const float4* __restrict__ xn4,
                                                     unsigned short* __restrict__ idxout,
                                                     float* __restrict__ S9) {
    __shared__ float smom[4][15][9];
    __shared__ __align__(16) float4 pts[1024];
    int w = threadIdx.x >> 6, lane = threadIdx.x & 63;
    int i = blockIdx.x * 4 + w;
    int b = i >> 12, n = i & (N - 1);
    const float4* xb = xn4 + b * N;
    float4 qv = xb[n];
    float d[64];
    #pragma unroll
    for (int ch = 0; ch < 4; ch++) {
        if (ch) __syncthreads();          // all waves done with previous chunk
        #pragma unroll
        for (int u = 0; u < 4; u++)
            pts[u * 256 + threadIdx.x] = xb[ch * 1024 + u * 256 + threadIdx.x];
        __syncthreads();
        #pragma unroll
        for (int j = 0; j < 16; j++) {
            float4 p = pts[j * 64 + lane];
            d[ch * 16 + j] = qv.w + p.w - 2.f * (qv.x * p.x + qv.y * p.y + qv.z * p.z);
        }
    }
    float cm[8];
    #pragma unroll
    for (int c = 0; c < 8; c++) {
        float v = d[c * 8];
        #pragma unroll
        for (int s = 1; s < 8; s++) v = fmaxf(v, d[c * 8 + s]);
        cm[c] = v;
    }
    float bv = cm[0];
    #pragma unroll
    for (int c = 1; c < 8; c++) bv = fmaxf(bv, cm[c]);

    int myj = 0;
    for (int r = 0; r < 16; r++) {
        float wv = wave_max_bcast(bv);
        unsigned long long msk = __ballot(bv == wv);
        int wl = __ffsll(msk) - 1;
        int gi = 0;
        if (lane == wl) {
            int cstar = 0; bool got = false;
            #pragma unroll
            for (int c = 0; c < 8; c++) {
                bool h = !got && (cm[c] == bv);
                cstar = h ? c : cstar;
                got = got || h;
            }
            int slot = 0;
            #pragma unroll
            for (int c = 0; c < 8; c++) {
                if (c == cstar) {   // 7 of 8 bodies skipped via execz
                    bool g2 = false;
                    #pragma unroll
                    for (int s = 0; s < 8; s++) {
                        bool h = !g2 && (d[c * 8 + s] == bv);
                        slot = h ? (c * 8 + s) : slot;
                        g2 = g2 || h;
                    }
                    #pragma unroll
                    for (int s = 0; s < 8; s++)
                        d[c * 8 + s] = (c * 8 + s == slot) ? -FLT_MAX : d[c * 8 + s];
                    float v = d[c * 8];
                    #pragma unroll
                    for (int s = 1; s < 8; s++) v = fmaxf(v, d[c * 8 + s]);
                    cm[c] = v;
                }
            }
            bv = cm[0];
            #pragma unroll
            for (int c = 1; c < 8; c++) bv = fmaxf(bv, cm[c]);
            gi = slot * 64 + lane;
        }
        int g = __shfl(gi, wl);
        if (lane == r - 1) myj = g;   // lanes 0..14 capture ranks 1..15
    }

    bool act = lane < 15;
    if (act) idxout[i * KNN + lane] = (unsigned short)myj;
    float4 pj = xb[act ? myj : n];
    float v0 = pj.x - qv.x, v1 = pj.y - qv.y, v2 = pj.z - qv.z;
    if (act) {
        float* mm = smom[w][lane];
        mm[0] = v0; mm[1] = v1; mm[2] = v2;
        mm[3] = v0 * v0; mm[4] = v1 * v1; mm[5] = v2 * v2;
        mm[6] = v0 * v1; mm[7] = v0 * v2; mm[8] = v1 * v2;
    }
    __syncthreads();
    int t = threadIdx.x;
    if (t < 36) {
        int wsel = t / 9, j = t % 9;
        float a = 0.f;
        #pragma unroll
        for (int u = 0; u < 15; u++) a += smom[wsel][u][j];
        atomicAdd(&S9[((blockIdx.x * 4 + wsel) & 63) * 9 + j], a);
    }
}

// ---------------- K5: closed-form BN2a affine + per-E fused (W2a*s, shift) float4 ----------------
__global__ void finalize_stats(const float* __restrict__ S9,
                               const float* __restrict__ g2a, const float* __restrict__ b2a,
                               const float* __restrict__ W2a,
                               const float* __restrict__ g2b, const float* __restrict__ b2b,
                               float* __restrict__ ab, float4* __restrict__ wsb) {
    const float cnt = (float)(BN_ * KNN);
    __shared__ float S[9];
    __shared__ float alpha[3], beta[3], mu[3], Ehh[3][3];
    int t = threadIdx.x;
    if (t < 9) {
        float a = 0.f;
        for (int u = 0; u < 64; u++) a += S9[u * 9 + t];
        S[t] = a;
    }
    __syncthreads();
    if (t == 0) {
        float m[3];
        float s2[3][3];
        s2[0][0] = S[3]; s2[1][1] = S[4]; s2[2][2] = S[5];
        s2[0][1] = s2[1][0] = S[6]; s2[0][2] = s2[2][0] = S[7]; s2[1][2] = s2[2][1] = S[8];
        for (int c = 0; c < 3; c++) {
            m[c] = S[c] / cnt;
            float var = s2[c][c] / cnt - m[c] * m[c];
            alpha[c] = g2a[c] * rsqrtf(var + EPS);
            beta[c]  = b2a[c] - m[c] * alpha[c];
            mu[c] = m[c];
            ab[c] = alpha[c]; ab[3 + c] = beta[c];
        }
        for (int c = 0; c < 3; c++)
            for (int cc = 0; cc < 3; cc++)
                Ehh[c][cc] = alpha[c] * alpha[cc] * (s2[c][cc] / cnt)
                           + alpha[c] * beta[cc] * m[c]
                           + beta[c] * alpha[cc] * m[cc]
                           + beta[c] * beta[cc];
    }
    __syncthreads();
    int e = t;
    float wv[3], Eh[3];
    for (int c = 0; c < 3; c++) { wv[c] = W2a[e * 3 + c]; Eh[c] = alpha[c] * mu[c] + beta[c]; }
    float mean = wv[0] * Eh[0] + wv[1] * Eh[1] + wv[2] * Eh[2];
    float m2 = 0.f;
    for (int c = 0; c < 3; c++)
        for (int cc = 0; cc < 3; cc++) m2 += wv[c] * wv[cc] * Ehh[c][cc];
    float var = m2 - mean * mean;
    float s = g2b[e] * rsqrtf(var + EPS);
    float4 o;
    o.x = wv[0] * s; o.y = wv[1] * s; o.z = wv[2] * s; o.w = b2b[e] - mean * s;
    wsb[e] = o;
}

// ---------------- K6: fused, P=8, 512 threads ----------------
// LDS-pipe analysis (R4): per block phase C issued 1024 ds_read_b128 (each
// wave re-read the FULL hh tile for each of its 2 f-tiles).  LDS pipe ~62us
// of the 85us.  Fix: hold BOTH f-tile A-operands in registers (same 16 global
// loads), read each hh fragment ONCE per point, feed 2 MFMA chains (R9: max
// 2 concurrent chains).  Phase-C reads 1024 -> 512 per block.
// __launch_bounds__(512,4): VGPR cap 128 (R1: cap 85 spilled; tripwire =
// FETCH/WRITE balloon).
__global__ void __launch_bounds__(512, 4) fused_final(
        const float4* __restrict__ xn4, const unsigned short* __restrict__ idx,
        const float* __restrict__ ab,
        const float4* __restrict__ wsb,
        const unsigned short* __restrict__ w2b_t,
        const float* __restrict__ W1, const float* __restrict__ bw1,
        const unsigned short* __restrict__ wf_t, const float* __restrict__ bfv,
        float* __restrict__ out) {
    __shared__ __align__(16) unsigned short hh_bf[64 * SR];    // row 16*(p&3)+k, col e (current pg)
    __shared__ __align__(16) unsigned short feat_bf[8 * SRF];  // row p (global 0..7), col f 0..511
    __shared__ __align__(16) float4 hhat4[P][16];              // (h0,h1,h2,-) per (p,k)
    int i0 = blockIdx.x * P;
    int t = threadIdx.x;
    int b = i0 >> 12, n0 = i0 & (N - 1);
    const float4* xb = xn4 + b * N;

    if (t < P * KNN) {   // phase A: gather + BN2a affine (120 threads, all 8 points)
        int p = t / KNN, k = t % KNN;
        int j = idx[(i0 + p) * KNN + k];
        float4 pj = xb[j];
        float4 pn = xb[n0 + p];
        float4 h;
        h.x = ab[0] * (pj.x - pn.x) + ab[3];
        h.y = ab[1] * (pj.y - pn.y) + ab[4];
        h.z = ab[2] * (pj.z - pn.z) + ab[5];
        h.w = 0.f;
        hhat4[p][k] = h;
    }
    __syncthreads();

    int w = t >> 6, lane = t & 63;
    int m = lane & 15, q = lane >> 4;

    #pragma unroll 1
    for (int pg = 0; pg < 2; pg++) {
        {   // phase B(pg): h = (W2a*s) @ hhat + shift, tanh-gelu -> packed bf16x2 LDS;
            // point_emb for the 4 points of this group.  Thread = (e-pair, point).
            int ep = t & 127;            // e-pair: e = 2*ep, 2*ep+1
            int pq = t >> 7;             // local point 0..3
            int p  = pg * 4 + pq;
            float4 wA = wsb[2 * ep];
            float4 wB = wsb[2 * ep + 1];
            float g0A = 0.f, g0B = 0.f;
            #pragma unroll
            for (int k = 0; k < KNN; k++) {
                float4 hv = hhat4[p][k];
                float vA = fmaf(wA.x, hv.x, fmaf(wA.y, hv.y, fmaf(wA.z, hv.z, wA.w)));
                float vB = fmaf(wB.x, hv.x, fmaf(wB.y, hv.y, fmaf(wB.z, hv.z, wB.w)));
                float gA = gelu_t(vA), gB = gelu_t(vB);
                *(unsigned int*)&hh_bf[(16 * pq + k) * SR + 2 * ep] = pkbf(gA, gB);
                if (k == 0) { g0A = gA; g0B = gB; }
            }
            *(unsigned int*)&hh_bf[(16 * pq + 15) * SR + 2 * ep] = pkbf(g0A, g0B);  // dup row
            float4 pv = xb[n0 + p];
            float peA = bw1[2 * ep] + W1[(2 * ep) * 3] * pv.x
                      + W1[(2 * ep) * 3 + 1] * pv.y + W1[(2 * ep) * 3 + 2] * pv.z;
            float peB = bw1[2 * ep + 1] + W1[(2 * ep + 1) * 3] * pv.x
                      + W1[(2 * ep + 1) * 3 + 1] * pv.y + W1[(2 * ep + 1) * 3 + 2] * pv.z;
            *(unsigned int*)&feat_bf[p * SRF + 2 * ep] = pkbf(peA, peB);
        }
        __syncthreads();

        {   // phase C(pg): A-operands for BOTH f-tiles resident in regs;
            // hh fragment read ONCE per point, feeds 2 MFMA chains.
            bf8 a0[8], a1[8];
            #pragma unroll
            for (int kb = 0; kb < 8; kb++) {
                a0[kb] = ld_bf8(w2b_t + (w * 2 + 0) * 4096 + kb * 512 + lane * 8);
                a1[kb] = ld_bf8(w2b_t + (w * 2 + 1) * 4096 + kb * 512 + lane * 8);
            }
            #pragma unroll 1
            for (int pp = 0; pp < 4; pp++) {
                bf8 hfr[8];
                #pragma unroll
                for (int kb = 0; kb < 8; kb++)
                    hfr[kb] = ld_bf8(&hh_bf[(16 * pp + m) * SR + kb * 32 + q * 8]);
                f4 acc0 = {0.f, 0.f, 0.f, 0.f};
                f4 acc1 = {0.f, 0.f, 0.f, 0.f};
                #pragma unroll
                for (int kb = 0; kb < 8; kb++) {
                    acc0 = __builtin_amdgcn_mfma_f32_16x16x32_bf16(hfr[kb], a0[kb], acc0, 0, 0, 0);
                    acc1 = __builtin_amdgcn_mfma_f32_16x16x32_bf16(hfr[kb], a1[kb], acc1, 0, 0, 0);
                }
                float mx0 = fmaxf(fmaxf(acc0[0], acc0[1]), fmaxf(acc0[2], acc0[3]));
                float mx1 = fmaxf(fmaxf(acc1[0], acc1[1]), fmaxf(acc1[2], acc1[3]));
                mx0 = fmaxf(mx0, __shfl_xor(mx0, 16));
                mx0 = fmaxf(mx0, __shfl_xor(mx0, 32));
                mx1 = fmaxf(mx1, __shfl_xor(mx1, 16));
                mx1 = fmaxf(mx1, __shfl_xor(mx1, 32));
                if (lane < 16) {
                    feat_bf[(pg * 4 + pp) * SRF + E + (w * 2 + 0) * 16 + lane] = f2bf(mx0);
                    feat_bf[(pg * 4 + pp) * SRF + E + (w * 2 + 1) * 16 + lane] = f2bf(mx1);
                }
            }
        }
        __syncthreads();
    }

    {   // phase D: wave w -> o-tiles {2w, 2w+1}; cols = 8 points (m&7)
        bf8 fb[16];
        #pragma unroll
        for (int kb = 0; kb < 16; kb++)
            fb[kb] = ld_bf8(&feat_bf[(m & 7) * SRF + kb * 32 + q * 8]);
        #pragma unroll
        for (int o2 = 0; o2 < 2; o2++) {
            int ot = w * 2 + o2;
            f4 acc = {0.f, 0.f, 0.f, 0.f};
            #pragma unroll
            for (int kb = 0; kb < 16; kb++) {
                bf8 a = ld_bf8(wf_t + ot * 8192 + kb * 512 + lane * 8);
                acc = __builtin_amdgcn_mfma_f32_16x16x32_bf16(a, fb[kb], acc, 0, 0, 0);
            }
            if (m < P) {   // col = m = point; row = ot*16 + 4q + reg
                int o0 = ot * 16 + 4 * q;
                out[(b * E + o0 + 0) * N + n0 + m] = acc[0] + bfv[o0 + 0];
                out[(b * E + o0 + 1) * N + n0 + m] = acc[1] + bfv[o0 + 1];
                out[(b * E + o0 + 2) * N + n0 + m] = acc[2] + bfv[o0 + 2];
                out[(b * E + o0 + 3) * N + n0 + m] = acc[3] + bfv[o0 + 3];
            }
        }
    }
}

extern "C" void kernel_launch(void* const* d_in, const int* in_sizes, int n_in,
                              void* d_out, int out_size, void* d_ws, size_t ws_size,
                              hipStream_t stream) {
    (void)in_sizes; (void)n_in; (void)out_size; (void)ws_size;
    const float* x   = (const float*)d_in[0];
    const float* g1  = (const float*)d_in[1];
    const float* b1  = (const float*)d_in[2];
    const float* W1  = (const float*)d_in[3];
    const float* bw1 = (const float*)d_in[4];
    const float* g2a = (const float*)d_in[5];
    const float* b2a = (const float*)d_in[6];
    const float* W2a = (const float*)d_in[7];
    const float* g2b = (const float*)d_in[8];
    const float* b2b = (const float*)d_in[9];
    const float* W2b = (const float*)d_in[10];
    const float* Wf  = (const float*)d_in[11];
    const float* bfv = (const float*)d_in[12];
    float* out = (float*)d_out;

    char* ws = (char*)d_ws;
    size_t off = 0;
    auto alloc = [&](size_t bytes) { size_t o = off; off = (off + bytes + 255) & ~(size_t)255; return o; };
    float4* xn4           = (float4*)(ws + alloc(sizeof(float4) * BN_));
    unsigned short* idx   = (unsigned short*)(ws + alloc(sizeof(unsigned short) * BN_ * KNN));
    float* bn1            = (float*)(ws + alloc(sizeof(float) * 8));
    float* S9             = (float*)(ws + alloc(sizeof(float) * 64 * 9));
    float* ab             = (float*)(ws + alloc(sizeof(float) * 8));
    float4* wsb           = (float4*)(ws + alloc(sizeof(float4) * E));
    unsigned short* w2bt  = (unsigned short*)(ws + alloc(sizeof(unsigned short) * E * E));
    unsigned short* wft   = (unsigned short*)(ws + alloc(sizeof(unsigned short) * E * 2 * E));

    hipMemsetAsync(S9, 0, sizeof(float) * 64 * 9, stream);

    bn1_stats<<<C, 256, 0, stream>>>(x, bn1);
    compute_xn_cvt<<<BN_ / 256 + (8192 + 16384) / 256, 256, 0, stream>>>(
        x, g1, b1, bn1, xn4, W2b, Wf, w2bt, wft);
    knn_kernel<<<BN_ / 4, 256, 0, stream>>>(xn4, idx, S9);
    finalize_stats<<<1, 256, 0, stream>>>(S9, g2a, b2a, W2a, g2b, b2b, ab, wsb);
    fused_final<<<BN_ / P, 512, 0, stream>>>(xn4, idx, ab, wsb, w2bt, W1, bw1, wft, bfv, out);
}

// Round 7
// 230.153 us; speedup vs baseline: 1.0085x; 1.0085x over previous
//
#include <hip/hip_runtime.h>
#include <float.h>
#include <math.h>

#define EPS 1e-5f
constexpr int B = 4, C = 3, N = 4096, E = 256;
constexpr int KNN = 15;            // 15 neighbors kept (top-16 minus rank 0)
constexpr int BN_ = B * N;         // 16384
constexpr int P = 8;               // points per block in fused kernel
constexpr int SR  = 264;           // hh_bf row stride (ushorts)
constexpr int SRF = 520;           // feat_bf row stride (ushorts)

typedef short bf8 __attribute__((ext_vector_type(8)));   // 8 bf16 in 4 VGPRs
typedef float f4  __attribute__((ext_vector_type(4)));

static __device__ __forceinline__ unsigned short f2bf(float f) {
    union { float f; unsigned int u; } v; v.f = f;
    unsigned int r = v.u + 0x7FFFu + ((v.u >> 16) & 1u);   // RTNE
    return (unsigned short)(r >> 16);
}
// packed 2xbf16 convert (RNE), lo = a, hi = b
static __device__ __forceinline__ unsigned int pkbf(float a, float b) {
    unsigned int r;
    asm("v_cvt_pk_bf16_f32 %0, %1, %2" : "=v"(r) : "v"(a), "v"(b));
    return r;
}
static __device__ __forceinline__ bf8 ld_bf8(const unsigned short* p) {
    return *(const bf8*)p;
}
// tanh-GELU: max |err| vs exact erf-gelu ~3e-4 (<< bf16 rounding).
static __device__ __forceinline__ float gelu_t(float v) {
    float z = v * fmaf(v * v, 0.07135482f, 1.59576912f);   // z = 2u
    float r = __builtin_amdgcn_rcpf(1.f + __expf(z));
    return fmaf(-v, r, v);
}

// DPP-based wave64 max: row_shr 1/2/4/8 then row_bcast 15/31; result in lane 63,
// broadcast via readlane. dpp_ctrl must be an ICE -> template parameter.
template <int CTRL>
static __device__ __forceinline__ float dppmax(float x) {
    int xi = __float_as_int(x);
    int yi = __builtin_amdgcn_update_dpp(xi, xi, CTRL, 0xF, 0xF, false);
    return fmaxf(x, __int_as_float(yi));
}
static __device__ __forceinline__ float wave_max_bcast(float x) {
    x = dppmax<0x111>(x);   // row_shr:1
    x = dppmax<0x112>(x);   // row_shr:2
    x = dppmax<0x114>(x);   // row_shr:4
    x = dppmax<0x118>(x);   // row_shr:8
    x = dppmax<0x142>(x);   // row_bcast:15
    x = dppmax<0x143>(x);   // row_bcast:31
    return __int_as_float(__builtin_amdgcn_readlane(__float_as_int(x), 63));
}

// ---------------- K1: per-channel mean/rstd of x over (B,N) ----------------
__global__ void bn1_stats(const float* __restrict__ x, float* __restrict__ bn1) {
    int c = blockIdx.x, t = threadIdx.x;
    float s = 0.f, ss = 0.f;
    for (int i4 = t; i4 < BN_ / 4; i4 += 256) {
        int b = i4 >> 10, n4 = i4 & 1023;
        float4 v = ((const float4*)(x + (b * C + c) * N))[n4];
        s += v.x + v.y + v.z + v.w;
        ss += v.x * v.x + v.y * v.y + v.z * v.z + v.w * v.w;
    }
    __shared__ float rs_[256], rss_[256];
    rs_[t] = s; rss_[t] = ss; __syncthreads();
    for (int w = 128; w > 0; w >>= 1) {
        if (t < w) { rs_[t] += rs_[t + w]; rss_[t] += rss_[t + w]; }
        __syncthreads();
    }
    if (t == 0) {
        float mu = rs_[0] / (float)BN_;
        float var = rss_[0] / (float)BN_ - mu * mu;
        bn1[c] = mu; bn1[3 + c] = rsqrtf(var + EPS);
    }
}

// ---------------- K2: xn4 AoS (blocks 0..63) + tile-lane-major bf16 weights ----------------
__global__ void compute_xn_cvt(const float* __restrict__ x,
                               const float* __restrict__ g1,
                               const float* __restrict__ b1,
                               const float* __restrict__ bn1,
                               float4* __restrict__ xn4,
                               const float* __restrict__ W2b, const float* __restrict__ Wf,
                               unsigned short* __restrict__ w2b_t, unsigned short* __restrict__ wf_t) {
    int blk = blockIdx.x;
    if (blk < BN_ / 256) {
        int i = blk * 256 + threadIdx.x;
        int b = i >> 12, n = i & (N - 1);
        float v[3];
        #pragma unroll
        for (int c = 0; c < C; c++)
            v[c] = (x[(b * C + c) * N + n] - bn1[c]) * bn1[3 + c] * g1[c] + b1[c];
        float4 o; o.x = v[0]; o.y = v[1]; o.z = v[2];
        o.w = v[0] * v[0] + v[1] * v[1] + v[2] * v[2];
        xn4[i] = o;
        return;
    }
    int ch = (blk - BN_ / 256) * 256 + threadIdx.x;   // chunk id (8 bf16 per chunk)
    if (ch < 8192) {               // w2b: 65536 elems = 8192 chunks
        int lane = ch & 63, kb = (ch >> 6) & 7, ft16 = ch >> 9;
        int row = ft16 * 16 + (lane & 15);
        int col = kb * 32 + (lane >> 4) * 8;
        #pragma unroll
        for (int j = 0; j < 8; j++)
            w2b_t[ch * 8 + j] = f2bf(W2b[row * 256 + col + j]);
    } else {                       // wf: 131072 elems = 16384 chunks
        int c2 = ch - 8192;
        int lane = c2 & 63, kb = (c2 >> 6) & 15, ot = c2 >> 10;
        int row = ot * 16 + (lane & 15);
        int col = kb * 32 + (lane >> 4) * 8;
        #pragma unroll
        for (int j = 0; j < 8; j++)
            wf_t[c2 * 8 + j] = f2bf(Wf[row * 512 + col + j]);
    }
}

// ---------------- K3: top-16 (largest d2), one WAVE per point ----------------
// R6 post-mortem: pts as float4 AoS gave 16B lane stride -> lanes {l,l+8,..}
// share a bank group = 8-WAY conflict on every ds_read_b128 (~35cy issue);
// per CU ~143K cy of LDS-pipe serialization.  Fix: SoA planes (x/y/z/w),
// 4x ds_read_b32 at 4B lane stride = 2-way = free (m136).  Same op order ->
// bit-identical d2 -> identical selection/tie behavior.
__global__ void __launch_bounds__(256, 4) knn_kernel(const float4* __restrict__ xn4,
                                                     unsigned short* __restrict__ idxout,
                                                     float* __restrict__ S9) {
    __shared__ float smom[4][15][9];
    __shared__ float ptx[1024], pty[1024], ptz[1024], ptw[1024];
    int w = threadIdx.x >> 6, lane = threadIdx.x & 63;
    int i = blockIdx.x * 4 + w;
    int b = i >> 12, n = i & (N - 1);
    const float4* xb = xn4 + b * N;
    float4 qv = xb[n];
    float d[64];
    #pragma unroll
    for (int ch = 0; ch < 4; ch++) {
        if (ch) __syncthreads();          // all waves done with previous chunk
        #pragma unroll
        for (int u = 0; u < 4; u++) {
            int s = u * 256 + threadIdx.x;
            float4 v = xb[ch * 1024 + s];
            ptx[s] = v.x; pty[s] = v.y; ptz[s] = v.z; ptw[s] = v.w;
        }
        __syncthreads();
        #pragma unroll
        for (int j = 0; j < 16; j++) {
            int s = j * 64 + lane;
            d[ch * 16 + j] = qv.w + ptw[s]
                - 2.f * (qv.x * ptx[s] + qv.y * pty[s] + qv.z * ptz[s]);
        }
    }
    float cm[8];
    #pragma unroll
    for (int c = 0; c < 8; c++) {
        float v = d[c * 8];
        #pragma unroll
        for (int s = 1; s < 8; s++) v = fmaxf(v, d[c * 8 + s]);
        cm[c] = v;
    }
    float bv = cm[0];
    #pragma unroll
    for (int c = 1; c < 8; c++) bv = fmaxf(bv, cm[c]);

    int myj = 0;
    for (int r = 0; r < 16; r++) {
        float wv = wave_max_bcast(bv);
        unsigned long long msk = __ballot(bv == wv);
        int wl = __ffsll(msk) - 1;
        int gi = 0;
        if (lane == wl) {
            int cstar = 0; bool got = false;
            #pragma unroll
            for (int c = 0; c < 8; c++) {
                bool h = !got && (cm[c] == bv);
                cstar = h ? c : cstar;
                got = got || h;
            }
            int slot = 0;
            #pragma unroll
            for (int c = 0; c < 8; c++) {
                if (c == cstar) {   // 7 of 8 bodies skipped via execz
                    bool g2 = false;
                    #pragma unroll
                    for (int s = 0; s < 8; s++) {
                        bool h = !g2 && (d[c * 8 + s] == bv);
                        slot = h ? (c * 8 + s) : slot;
                        g2 = g2 || h;
                    }
                    #pragma unroll
                    for (int s = 0; s < 8; s++)
                        d[c * 8 + s] = (c * 8 + s == slot) ? -FLT_MAX : d[c * 8 + s];
                    float v = d[c * 8];
                    #pragma unroll
                    for (int s = 1; s < 8; s++) v = fmaxf(v, d[c * 8 + s]);
                    cm[c] = v;
                }
            }
            bv = cm[0];
            #pragma unroll
            for (int c = 1; c < 8; c++) bv = fmaxf(bv, cm[c]);
            gi = slot * 64 + lane;
        }
        int g = __shfl(gi, wl);
        if (lane == r - 1) myj = g;   // lanes 0..14 capture ranks 1..15
    }

    bool act = lane < 15;
    if (act) idxout[i * KNN + lane] = (unsigned short)myj;
    float4 pj = xb[act ? myj : n];
    float v0 = pj.x - qv.x, v1 = pj.y - qv.y, v2 = pj.z - qv.z;
    if (act) {
        float* mm = smom[w][lane];
        mm[0] = v0; mm[1] = v1; mm[2] = v2;
        mm[3] = v0 * v0; mm[4] = v1 * v1; mm[5] = v2 * v2;
        mm[6] = v0 * v1; mm[7] = v0 * v2; mm[8] = v1 * v2;
    }
    __syncthreads();
    int t = threadIdx.x;
    if (t < 36) {
        int wsel = t / 9, j = t % 9;
        float a = 0.f;
        #pragma unroll
        for (int u = 0; u < 15; u++) a += smom[wsel][u][j];
        atomicAdd(&S9[((blockIdx.x * 4 + wsel) & 63) * 9 + j], a);
    }
}

// ---------------- K5: closed-form BN2a affine + per-E fused (W2a*s, shift) float4 ----------------
__global__ void finalize_stats(const float* __restrict__ S9,
                               const float* __restrict__ g2a, const float* __restrict__ b2a,
                               const float* __restrict__ W2a,
                               const float* __restrict__ g2b, const float* __restrict__ b2b,
                               float* __restrict__ ab, float4* __restrict__ wsb) {
    const float cnt = (float)(BN_ * KNN);
    __shared__ float S[9];
    __shared__ float alpha[3], beta[3], mu[3], Ehh[3][3];
    int t = threadIdx.x;
    if (t < 9) {
        float a = 0.f;
        for (int u = 0; u < 64; u++) a += S9[u * 9 + t];
        S[t] = a;
    }
    __syncthreads();
    if (t == 0) {
        float m[3];
        float s2[3][3];
        s2[0][0] = S[3]; s2[1][1] = S[4]; s2[2][2] = S[5];
        s2[0][1] = s2[1][0] = S[6]; s2[0][2] = s2[2][0] = S[7]; s2[1][2] = s2[2][1] = S[8];
        for (int c = 0; c < 3; c++) {
            m[c] = S[c] / cnt;
            float var = s2[c][c] / cnt - m[c] * m[c];
            alpha[c] = g2a[c] * rsqrtf(var + EPS);
            beta[c]  = b2a[c] - m[c] * alpha[c];
            mu[c] = m[c];
            ab[c] = alpha[c]; ab[3 + c] = beta[c];
        }
        for (int c = 0; c < 3; c++)
            for (int cc = 0; cc < 3; cc++)
                Ehh[c][cc] = alpha[c] * alpha[cc] * (s2[c][cc] / cnt)
                           + alpha[c] * beta[cc] * m[c]
                           + beta[c] * alpha[cc] * m[cc]
                           + beta[c] * beta[cc];
    }
    __syncthreads();
    int e = t;
    float wv[3], Eh[3];
    for (int c = 0; c < 3; c++) { wv[c] = W2a[e * 3 + c]; Eh[c] = alpha[c] * mu[c] + beta[c]; }
    float mean = wv[0] * Eh[0] + wv[1] * Eh[1] + wv[2] * Eh[2];
    float m2 = 0.f;
    for (int c = 0; c < 3; c++)
        for (int cc = 0; cc < 3; cc++) m2 += wv[c] * wv[cc] * Ehh[c][cc];
    float var = m2 - mean * mean;
    float s = g2b[e] * rsqrtf(var + EPS);
    float4 o;
    o.x = wv[0] * s; o.y = wv[1] * s; o.z = wv[2] * s; o.w = b2b[e] - mean * s;
    wsb[e] = o;
}

// ---------------- K6: fused, P=8, 512 threads ----------------
// R6 spill fix: WRITE 41MB / FETCH 5.9MB = scratch signature (~24B/thread).
// Peak-pressure reduction, accumulation order per-acc UNCHANGED (bit-identical):
//  - phase C: hfr loaded in two scoped 4-kb halves (16 regs live, was 32);
//  - phase D: fb loaded in two 8-kb halves (32 regs live, was 64), wf_t
//    streamed per-half.  a0/a1 stay resident (R6's read dedup kept).
__global__ void __launch_bounds__(512, 4) fused_final(
        const float4* __restrict__ xn4, const unsigned short* __restrict__ idx,
        const float* __restrict__ ab,
        const float4* __restrict__ wsb,
        const unsigned short* __restrict__ w2b_t,
        const float* __restrict__ W1, const float* __restrict__ bw1,
        const unsigned short* __restrict__ wf_t, const float* __restrict__ bfv,
        float* __restrict__ out) {
    __shared__ __align__(16) unsigned short hh_bf[64 * SR];    // row 16*(p&3)+k, col e (current pg)
    __shared__ __align__(16) unsigned short feat_bf[8 * SRF];  // row p (global 0..7), col f 0..511
    __shared__ __align__(16) float4 hhat4[P][16];              // (h0,h1,h2,-) per (p,k)
    int i0 = blockIdx.x * P;
    int t = threadIdx.x;
    int b = i0 >> 12, n0 = i0 & (N - 1);
    const float4* xb = xn4 + b * N;

    if (t < P * KNN) {   // phase A: gather + BN2a affine (120 threads, all 8 points)
        int p = t / KNN, k = t % KNN;
        int j = idx[(i0 + p) * KNN + k];
        float4 pj = xb[j];
        float4 pn = xb[n0 + p];
        float4 h;
        h.x = ab[0] * (pj.x - pn.x) + ab[3];
        h.y = ab[1] * (pj.y - pn.y) + ab[4];
        h.z = ab[2] * (pj.z - pn.z) + ab[5];
        h.w = 0.f;
        hhat4[p][k] = h;
    }
    __syncthreads();

    int w = t >> 6, lane = t & 63;
    int m = lane & 15, q = lane >> 4;

    #pragma unroll 1
    for (int pg = 0; pg < 2; pg++) {
        {   // phase B(pg): h = (W2a*s) @ hhat + shift, tanh-gelu -> packed bf16x2 LDS;
            // point_emb for the 4 points of this group.  Thread = (e-pair, point).
            int ep = t & 127;            // e-pair: e = 2*ep, 2*ep+1
            int pq = t >> 7;             // local point 0..3
            int p  = pg * 4 + pq;
            float4 wA = wsb[2 * ep];
            float4 wB = wsb[2 * ep + 1];
            float g0A = 0.f, g0B = 0.f;
            #pragma unroll
            for (int k = 0; k < KNN; k++) {
                float4 hv = hhat4[p][k];
                float vA = fmaf(wA.x, hv.x, fmaf(wA.y, hv.y, fmaf(wA.z, hv.z, wA.w)));
                float vB = fmaf(wB.x, hv.x, fmaf(wB.y, hv.y, fmaf(wB.z, hv.z, wB.w)));
                float gA = gelu_t(vA), gB = gelu_t(vB);
                *(unsigned int*)&hh_bf[(16 * pq + k) * SR + 2 * ep] = pkbf(gA, gB);
                if (k == 0) { g0A = gA; g0B = gB; }
            }
            *(unsigned int*)&hh_bf[(16 * pq + 15) * SR + 2 * ep] = pkbf(g0A, g0B);  // dup row
            float4 pv = xb[n0 + p];
            float peA = bw1[2 * ep] + W1[(2 * ep) * 3] * pv.x
                      + W1[(2 * ep) * 3 + 1] * pv.y + W1[(2 * ep) * 3 + 2] * pv.z;
            float peB = bw1[2 * ep + 1] + W1[(2 * ep + 1) * 3] * pv.x
                      + W1[(2 * ep + 1) * 3 + 1] * pv.y + W1[(2 * ep + 1) * 3 + 2] * pv.z;
            *(unsigned int*)&feat_bf[p * SRF + 2 * ep] = pkbf(peA, peB);
        }
        __syncthreads();

        {   // phase C(pg): A-operands for BOTH f-tiles resident; hh fragment
            // read ONCE per point in two scoped 4-kb halves, feeds 2 chains.
            bf8 a0[8], a1[8];
            #pragma unroll
            for (int kb = 0; kb < 8; kb++) {
                a0[kb] = ld_bf8(w2b_t + (w * 2 + 0) * 4096 + kb * 512 + lane * 8);
                a1[kb] = ld_bf8(w2b_t + (w * 2 + 1) * 4096 + kb * 512 + lane * 8);
            }
            #pragma unroll 1
            for (int pp = 0; pp < 4; pp++) {
                const unsigned short* hrow = &hh_bf[(16 * pp + m) * SR + q * 8];
                f4 acc0 = {0.f, 0.f, 0.f, 0.f};
                f4 acc1 = {0.f, 0.f, 0.f, 0.f};
                {   // kb 0..3
                    bf8 h0 = ld_bf8(hrow +   0), h1 = ld_bf8(hrow +  32);
                    bf8 h2 = ld_bf8(hrow +  64), h3 = ld_bf8(hrow +  96);
                    acc0 = __builtin_amdgcn_mfma_f32_16x16x32_bf16(h0, a0[0], acc0, 0, 0, 0);
                    acc1 = __builtin_amdgcn_mfma_f32_16x16x32_bf16(h0, a1[0], acc1, 0, 0, 0);
                    acc0 = __builtin_amdgcn_mfma_f32_16x16x32_bf16(h1, a0[1], acc0, 0, 0, 0);
                    acc1 = __builtin_amdgcn_mfma_f32_16x16x32_bf16(h1, a1[1], acc1, 0, 0, 0);
                    acc0 = __builtin_amdgcn_mfma_f32_16x16x32_bf16(h2, a0[2], acc0, 0, 0, 0);
                    acc1 = __builtin_amdgcn_mfma_f32_16x16x32_bf16(h2, a1[2], acc1, 0, 0, 0);
                    acc0 = __builtin_amdgcn_mfma_f32_16x16x32_bf16(h3, a0[3], acc0, 0, 0, 0);
                    acc1 = __builtin_amdgcn_mfma_f32_16x16x32_bf16(h3, a1[3], acc1, 0, 0, 0);
                }
                {   // kb 4..7
                    bf8 h4 = ld_bf8(hrow + 128), h5 = ld_bf8(hrow + 160);
                    bf8 h6 = ld_bf8(hrow + 192), h7 = ld_bf8(hrow + 224);
                    acc0 = __builtin_amdgcn_mfma_f32_16x16x32_bf16(h4, a0[4], acc0, 0, 0, 0);
                    acc1 = __builtin_amdgcn_mfma_f32_16x16x32_bf16(h4, a1[4], acc1, 0, 0, 0);
                    acc0 = __builtin_amdgcn_mfma_f32_16x16x32_bf16(h5, a0[5], acc0, 0, 0, 0);
                    acc1 = __builtin_amdgcn_mfma_f32_16x16x32_bf16(h5, a1[5], acc1, 0, 0, 0);
                    acc0 = __builtin_amdgcn_mfma_f32_16x16x32_bf16(h6, a0[6], acc0, 0, 0, 0);
                    acc1 = __builtin_amdgcn_mfma_f32_16x16x32_bf16(h6, a1[6], acc1, 0, 0, 0);
                    acc0 = __builtin_amdgcn_mfma_f32_16x16x32_bf16(h7, a0[7], acc0, 0, 0, 0);
                    acc1 = __builtin_amdgcn_mfma_f32_16x16x32_bf16(h7, a1[7], acc1, 0, 0, 0);
                }
                float mx0 = fmaxf(fmaxf(acc0[0], acc0[1]), fmaxf(acc0[2], acc0[3]));
                float mx1 = fmaxf(fmaxf(acc1[0], acc1[1]), fmaxf(acc1[2], acc1[3]));
                mx0 = fmaxf(mx0, __shfl_xor(mx0, 16));
                mx0 = fmaxf(mx0, __shfl_xor(mx0, 32));
                mx1 = fmaxf(mx1, __shfl_xor(mx1, 16));
                mx1 = fmaxf(mx1, __shfl_xor(mx1, 32));
                if (lane < 16) {
                    feat_bf[(pg * 4 + pp) * SRF + E + (w * 2 + 0) * 16 + lane] = f2bf(mx0);
                    feat_bf[(pg * 4 + pp) * SRF + E + (w * 2 + 1) * 16 + lane] = f2bf(mx1);
                }
            }
        }
        __syncthreads();
    }

    {   // phase D: wave w -> o-tiles {2w, 2w+1}; cols = 8 points (m&7).
        // fb in two 8-kb halves (32 regs live); per-acc kb order still 0..15.
        f4 accD0 = {0.f, 0.f, 0.f, 0.f};
        f4 accD1 = {0.f, 0.f, 0.f, 0.f};
        #pragma unroll 1
        for (int hf = 0; hf < 2; hf++) {
            bf8 fb8[8];
            #pragma unroll
            for (int k2 = 0; k2 < 8; k2++)
                fb8[k2] = ld_bf8(&feat_bf[(m & 7) * SRF + (hf * 8 + k2) * 32 + q * 8]);
            #pragma unroll
            for (int k2 = 0; k2 < 8; k2++) {
                bf8 aa = ld_bf8(wf_t + (w * 2 + 0) * 8192 + (hf * 8 + k2) * 512 + lane * 8);
                accD0 = __builtin_amdgcn_mfma_f32_16x16x32_bf16(aa, fb8[k2], accD0, 0, 0, 0);
            }
            #pragma unroll
            for (int k2 = 0; k2 < 8; k2++) {
                bf8 aa = ld_bf8(wf_t + (w * 2 + 1) * 8192 + (hf * 8 + k2) * 512 + lane * 8);
                accD1 = __builtin_amdgcn_mfma_f32_16x16x32_bf16(aa, fb8[k2], accD1, 0, 0, 0);
            }
        }
        if (m < P) {   // col = m = point; row = ot*16 + 4q + reg
            int o0 = (w * 2 + 0) * 16 + 4 * q;
            out[(b * E + o0 + 0) * N + n0 + m] = accD0[0] + bfv[o0 + 0];
            out[(b * E + o0 + 1) * N + n0 + m] = accD0[1] + bfv[o0 + 1];
            out[(b * E + o0 + 2) * N + n0 + m] = accD0[2] + bfv[o0 + 2];
            out[(b * E + o0 + 3) * N + n0 + m] = accD0[3] + bfv[o0 + 3];
            int o1 = (w * 2 + 1) * 16 + 4 * q;
            out[(b * E + o1 + 0) * N + n0 + m] = accD1[0] + bfv[o1 + 0];
            out[(b * E + o1 + 1) * N + n0 + m] = accD1[1] + bfv[o1 + 1];
            out[(b * E + o1 + 2) * N + n0 + m] = accD1[2] + bfv[o1 + 2];
            out[(b * E + o1 + 3) * N + n0 + m] = accD1[3] + bfv[o1 + 3];
        }
    }
}

extern "C" void kernel_launch(void* const* d_in, const int* in_sizes, int n_in,
                              void* d_out, int out_size, void* d_ws, size_t ws_size,
                              hipStream_t stream) {
    (void)in_sizes; (void)n_in; (void)out_size; (void)ws_size;
    const float* x   = (const float*)d_in[0];
    const float* g1  = (const float*)d_in[1];
    const float* b1  = (const float*)d_in[2];
    const float* W1  = (const float*)d_in[3];
    const float* bw1 = (const float*)d_in[4];
    const float* g2a = (const float*)d_in[5];
    const float* b2a = (const float*)d_in[6];
    const float* W2a = (const float*)d_in[7];
    const float* g2b = (const float*)d_in[8];
    const float* b2b = (const float*)d_in[9];
    const float* W2b = (const float*)d_in[10];
    const float* Wf  = (const float*)d_in[11];
    const float* bfv = (const float*)d_in[12];
    float* out = (float*)d_out;

    char* ws = (char*)d_ws;
    size_t off = 0;
    auto alloc = [&](size_t bytes) { size_t o = off; off = (off + bytes + 255) & ~(size_t)255; return o; };
    float4* xn4           = (float4*)(ws + alloc(sizeof(float4) * BN_));
    unsigned short* idx   = (unsigned short*)(ws + alloc(sizeof(unsigned short) * BN_ * KNN));
    float* bn1            = (float*)(ws + alloc(sizeof(float) * 8));
    float* S9             = (float*)(ws + alloc(sizeof(float) * 64 * 9));
    float* ab             = (float*)(ws + alloc(sizeof(float) * 8));
    float4* wsb           = (float4*)(ws + alloc(sizeof(float4) * E));
    unsigned short* w2bt  = (unsigned short*)(ws + alloc(sizeof(unsigned short) * E * E));
    unsigned short* wft   = (unsigned short*)(ws + alloc(sizeof(unsigned short) * E * 2 * E));

    hipMemsetAsync(S9, 0, sizeof(float) * 64 * 9, stream);

    bn1_stats<<<C, 256, 0, stream>>>(x, bn1);
    compute_xn_cvt<<<BN_ / 256 + (8192 + 16384) / 256, 256, 0, stream>>>(
        x, g1, b1, bn1, xn4, W2b, Wf, w2bt, wft);
    knn_kernel<<<BN_ / 4, 256, 0, stream>>>(xn4, idx, S9);
    finalize_stats<<<1, 256, 0, stream>>>(S9, g2a, b2a, W2a, g2b, b2b, ab, wsb);
    fused_final<<<BN_ / P, 512, 0, stream>>>(xn4, idx, ab, wsb, w2bt, W1, bw1, wft, bfv, out);
}

// Round 8
// 218.077 us; speedup vs baseline: 1.0643x; 1.0554x over previous
//
#include <hip/hip_runtime.h>
#include <float.h>
#include <math.h>

#define EPS 1e-5f
constexpr int B = 4, C = 3, N = 4096, E = 256;
constexpr int KNN = 15;            // 15 neighbors kept (top-16 minus rank 0)
constexpr int BN_ = B * N;         // 16384
constexpr int P = 8;               // points per block in fused kernel
constexpr int SR  = 264;           // hh_bf row stride (ushorts)
constexpr int SRF = 520;           // feat_bf row stride (ushorts)

typedef short bf8 __attribute__((ext_vector_type(8)));   // 8 bf16 in 4 VGPRs
typedef float f4  __attribute__((ext_vector_type(4)));

static __device__ __forceinline__ unsigned short f2bf(float f) {
    union { float f; unsigned int u; } v; v.f = f;
    unsigned int r = v.u + 0x7FFFu + ((v.u >> 16) & 1u);   // RTNE
    return (unsigned short)(r >> 16);
}
// packed 2xbf16 convert (RNE), lo = a, hi = b
static __device__ __forceinline__ unsigned int pkbf(float a, float b) {
    unsigned int r;
    asm("v_cvt_pk_bf16_f32 %0, %1, %2" : "=v"(r) : "v"(a), "v"(b));
    return r;
}
static __device__ __forceinline__ bf8 ld_bf8(const unsigned short* p) {
    return *(const bf8*)p;
}
// tanh-GELU: max |err| vs exact erf-gelu ~3e-4 (<< bf16 rounding).
static __device__ __forceinline__ float gelu_t(float v) {
    float z = v * fmaf(v * v, 0.07135482f, 1.59576912f);   // z = 2u
    float r = __builtin_amdgcn_rcpf(1.f + __expf(z));
    return fmaf(-v, r, v);
}

// DPP-based wave64 max: row_shr 1/2/4/8 then row_bcast 15/31; result in lane 63,
// broadcast via readlane. dpp_ctrl must be an ICE -> template parameter.
template <int CTRL>
static __device__ __forceinline__ float dppmax(float x) {
    int xi = __float_as_int(x);
    int yi = __builtin_amdgcn_update_dpp(xi, xi, CTRL, 0xF, 0xF, false);
    return fmaxf(x, __int_as_float(yi));
}
static __device__ __forceinline__ float wave_max_bcast(float x) {
    x = dppmax<0x111>(x);   // row_shr:1
    x = dppmax<0x112>(x);   // row_shr:2
    x = dppmax<0x114>(x);   // row_shr:4
    x = dppmax<0x118>(x);   // row_shr:8
    x = dppmax<0x142>(x);   // row_bcast:15
    x = dppmax<0x143>(x);   // row_bcast:31
    return __int_as_float(__builtin_amdgcn_readlane(__float_as_int(x), 63));
}

// ---------------- K1: per-channel mean/rstd of x over (B,N); block C zeroes S9 ----------------
__global__ void bn1_stats(const float* __restrict__ x, float* __restrict__ bn1,
                          float* __restrict__ S9) {
    int c = blockIdx.x, t = threadIdx.x;
    if (c == C) {                      // absorbed memset: one fewer dispatch
        for (int u = t; u < 64 * 9; u += 256) S9[u] = 0.f;
        return;
    }
    float s = 0.f, ss = 0.f;
    for (int i4 = t; i4 < BN_ / 4; i4 += 256) {
        int b = i4 >> 10, n4 = i4 & 1023;
        float4 v = ((const float4*)(x + (b * C + c) * N))[n4];
        s += v.x + v.y + v.z + v.w;
        ss += v.x * v.x + v.y * v.y + v.z * v.z + v.w * v.w;
    }
    __shared__ float rs_[256], rss_[256];
    rs_[t] = s; rss_[t] = ss; __syncthreads();
    for (int w = 128; w > 0; w >>= 1) {
        if (t < w) { rs_[t] += rs_[t + w]; rss_[t] += rss_[t + w]; }
        __syncthreads();
    }
    if (t == 0) {
        float mu = rs_[0] / (float)BN_;
        float var = rss_[0] / (float)BN_ - mu * mu;
        bn1[c] = mu; bn1[3 + c] = rsqrtf(var + EPS);
    }
}

// ---------------- K2: xn4 AoS (blocks 0..63) + tile-lane-major bf16 weights ----------------
__global__ void compute_xn_cvt(const float* __restrict__ x,
                               const float* __restrict__ g1,
                               const float* __restrict__ b1,
                               const float* __restrict__ bn1,
                               float4* __restrict__ xn4,
                               const float* __restrict__ W2b, const float* __restrict__ Wf,
                               unsigned short* __restrict__ w2b_t, unsigned short* __restrict__ wf_t) {
    int blk = blockIdx.x;
    if (blk < BN_ / 256) {
        int i = blk * 256 + threadIdx.x;
        int b = i >> 12, n = i & (N - 1);
        float v[3];
        #pragma unroll
        for (int c = 0; c < C; c++)
            v[c] = (x[(b * C + c) * N + n] - bn1[c]) * bn1[3 + c] * g1[c] + b1[c];
        float4 o; o.x = v[0]; o.y = v[1]; o.z = v[2];
        o.w = v[0] * v[0] + v[1] * v[1] + v[2] * v[2];
        xn4[i] = o;
        return;
    }
    int ch = (blk - BN_ / 256) * 256 + threadIdx.x;   // chunk id (8 bf16 per chunk)
    if (ch < 8192) {               // w2b: 65536 elems = 8192 chunks
        int lane = ch & 63, kb = (ch >> 6) & 7, ft16 = ch >> 9;
        int row = ft16 * 16 + (lane & 15);
        int col = kb * 32 + (lane >> 4) * 8;
        #pragma unroll
        for (int j = 0; j < 8; j++)
            w2b_t[ch * 8 + j] = f2bf(W2b[row * 256 + col + j]);
    } else {                       // wf: 131072 elems = 16384 chunks
        int c2 = ch - 8192;
        int lane = c2 & 63, kb = (c2 >> 6) & 15, ot = c2 >> 10;
        int row = ot * 16 + (lane & 15);
        int col = kb * 32 + (lane >> 4) * 8;
        #pragma unroll
        for (int j = 0; j < 8; j++)
            wf_t[c2 * 8 + j] = f2bf(Wf[row * 512 + col + j]);
    }
}

// ---------------- K3: top-16 (largest d2), one WAVE per point ----------------
__global__ void __launch_bounds__(256, 4) knn_kernel(const float4* __restrict__ xn4,
                                                     unsigned short* __restrict__ idxout,
                                                     float* __restrict__ S9) {
    __shared__ float smom[4][15][9];
    __shared__ float ptx[1024], pty[1024], ptz[1024], ptw[1024];
    int w = threadIdx.x >> 6, lane = threadIdx.x & 63;
    int i = blockIdx.x * 4 + w;
    int b = i >> 12, n = i & (N - 1);
    const float4* xb = xn4 + b * N;
    float4 qv = xb[n];
    float d[64];
    #pragma unroll
    for (int ch = 0; ch < 4; ch++) {
        if (ch) __syncthreads();          // all waves done with previous chunk
        #pragma unroll
        for (int u = 0; u < 4; u++) {
            int s = u * 256 + threadIdx.x;
            float4 v = xb[ch * 1024 + s];
            ptx[s] = v.x; pty[s] = v.y; ptz[s] = v.z; ptw[s] = v.w;
        }
        __syncthreads();
        #pragma unroll
        for (int j = 0; j < 16; j++) {
            int s = j * 64 + lane;
            d[ch * 16 + j] = qv.w + ptw[s]
                - 2.f * (qv.x * ptx[s] + qv.y * pty[s] + qv.z * ptz[s]);
        }
    }
    float cm[8];
    #pragma unroll
    for (int c = 0; c < 8; c++) {
        float v = d[c * 8];
        #pragma unroll
        for (int s = 1; s < 8; s++) v = fmaxf(v, d[c * 8 + s]);
        cm[c] = v;
    }
    float bv = cm[0];
    #pragma unroll
    for (int c = 1; c < 8; c++) bv = fmaxf(bv, cm[c]);

    int myj = 0;
    for (int r = 0; r < 16; r++) {
        float wv = wave_max_bcast(bv);
        unsigned long long msk = __ballot(bv == wv);
        int wl = __ffsll(msk) - 1;
        int gi = 0;
        if (lane == wl) {
            int cstar = 0; bool got = false;
            #pragma unroll
            for (int c = 0; c < 8; c++) {
                bool h = !got && (cm[c] == bv);
                cstar = h ? c : cstar;
                got = got || h;
            }
            int slot = 0;
            #pragma unroll
            for (int c = 0; c < 8; c++) {
                if (c == cstar) {   // 7 of 8 bodies skipped via execz
                    bool g2 = false;
                    #pragma unroll
                    for (int s = 0; s < 8; s++) {
                        bool h = !g2 && (d[c * 8 + s] == bv);
                        slot = h ? (c * 8 + s) : slot;
                        g2 = g2 || h;
                    }
                    #pragma unroll
                    for (int s = 0; s < 8; s++)
                        d[c * 8 + s] = (c * 8 + s == slot) ? -FLT_MAX : d[c * 8 + s];
                    float v = d[c * 8];
                    #pragma unroll
                    for (int s = 1; s < 8; s++) v = fmaxf(v, d[c * 8 + s]);
                    cm[c] = v;
                }
            }
            bv = cm[0];
            #pragma unroll
            for (int c = 1; c < 8; c++) bv = fmaxf(bv, cm[c]);
            gi = slot * 64 + lane;
        }
        int g = __shfl(gi, wl);
        if (lane == r - 1) myj = g;   // lanes 0..14 capture ranks 1..15
    }

    bool act = lane < 15;
    if (act) idxout[i * KNN + lane] = (unsigned short)myj;
    float4 pj = xb[act ? myj : n];
    float v0 = pj.x - qv.x, v1 = pj.y - qv.y, v2 = pj.z - qv.z;
    if (act) {
        float* mm = smom[w][lane];
        mm[0] = v0; mm[1] = v1; mm[2] = v2;
        mm[3] = v0 * v0; mm[4] = v1 * v1; mm[5] = v2 * v2;
        mm[6] = v0 * v1; mm[7] = v0 * v2; mm[8] = v1 * v2;
    }
    __syncthreads();
    int t = threadIdx.x;
    if (t < 36) {
        int wsel = t / 9, j = t % 9;
        float a = 0.f;
        #pragma unroll
        for (int u = 0; u < 15; u++) a += smom[wsel][u][j];
        atomicAdd(&S9[((blockIdx.x * 4 + wsel) & 63) * 9 + j], a);
    }
}

// ---------------- K5: closed-form BN2a affine + per-E fused (W2a*s, shift) float4 ----------------
__global__ void finalize_stats(const float* __restrict__ S9,
                               const float* __restrict__ g2a, const float* __restrict__ b2a,
                               const float* __restrict__ W2a,
                               const float* __restrict__ g2b, const float* __restrict__ b2b,
                               float* __restrict__ ab, float4* __restrict__ wsb) {
    const float cnt = (float)(BN_ * KNN);
    __shared__ float S[9];
    __shared__ float alpha[3], beta[3], mu[3], Ehh[3][3];
    int t = threadIdx.x;
    if (t < 9) {
        float a = 0.f;
        for (int u = 0; u < 64; u++) a += S9[u * 9 + t];
        S[t] = a;
    }
    __syncthreads();
    if (t == 0) {
        float m[3];
        float s2[3][3];
        s2[0][0] = S[3]; s2[1][1] = S[4]; s2[2][2] = S[5];
        s2[0][1] = s2[1][0] = S[6]; s2[0][2] = s2[2][0] = S[7]; s2[1][2] = s2[2][1] = S[8];
        for (int c = 0; c < 3; c++) {
            m[c] = S[c] / cnt;
            float var = s2[c][c] / cnt - m[c] * m[c];
            alpha[c] = g2a[c] * rsqrtf(var + EPS);
            beta[c]  = b2a[c] - m[c] * alpha[c];
            mu[c] = m[c];
            ab[c] = alpha[c]; ab[3 + c] = beta[c];
        }
        for (int c = 0; c < 3; c++)
            for (int cc = 0; cc < 3; cc++)
                Ehh[c][cc] = alpha[c] * alpha[cc] * (s2[c][cc] / cnt)
                           + alpha[c] * beta[cc] * m[c]
                           + beta[c] * alpha[cc] * m[cc]
                           + beta[c] * beta[cc];
    }
    __syncthreads();
    int e = t;
    float wv[3], Eh[3];
    for (int c = 0; c < 3; c++) { wv[c] = W2a[e * 3 + c]; Eh[c] = alpha[c] * mu[c] + beta[c]; }
    float mean = wv[0] * Eh[0] + wv[1] * Eh[1] + wv[2] * Eh[2];
    float m2 = 0.f;
    for (int c = 0; c < 3; c++)
        for (int cc = 0; cc < 3; cc++) m2 += wv[c] * wv[cc] * Ehh[c][cc];
    float var = m2 - mean * mean;
    float s = g2b[e] * rsqrtf(var + EPS);
    float4 o;
    o.x = wv[0] * s; o.y = wv[1] * s; o.z = wv[2] * s; o.w = b2b[e] - mean * s;
    wsb[e] = o;
}

// ---------------- K6: fused, P=8, 512 threads ----------------
// R7 lesson: (512,4) made the allocator hold 64 VGPR + ~25B/thread scratch
// (WRITE 41MB).  (512,2) lifts the cap to 256 -> no spill (tripwire: WRITE
// must return to ~16.4MB).  hh double-buffered (LDS ~76KB, 2 blocks/CU =
// measured residency anyway) -> schedule A | B0 | {B1; C0} | C1 | D: one
// fewer barrier, and waves drift through {B1;C0} at staggered phases ->
// B1 VALU overlaps C0 MFMA across waves (m114 mechanism).
__global__ void __launch_bounds__(512, 2) fused_final(
        const float4* __restrict__ xn4, const unsigned short* __restrict__ idx,
        const float* __restrict__ ab,
        const float4* __restrict__ wsb,
        const unsigned short* __restrict__ w2b_t,
        const float* __restrict__ W1, const float* __restrict__ bw1,
        const unsigned short* __restrict__ wf_t, const float* __restrict__ bfv,
        float* __restrict__ out) {
    __shared__ __align__(16) unsigned short hh_bf[2][64 * SR];  // [pg][row 16*pq+k][col e]
    __shared__ __align__(16) unsigned short feat_bf[8 * SRF];   // row p, col f 0..511
    __shared__ __align__(16) float4 hhat4[P][16];               // (h0,h1,h2,-) per (p,k)
    int i0 = blockIdx.x * P;
    int t = threadIdx.x;
    int b = i0 >> 12, n0 = i0 & (N - 1);
    const float4* xb = xn4 + b * N;

    int w = t >> 6, lane = t & 63;
    int m = lane & 15, q = lane >> 4;

    // phase B(pg): h = (W2a*s) @ hhat + shift, tanh-gelu -> packed bf16x2 into
    // hh_bf[pg]; point_emb for the 4 points of the group.  Thread = (e-pair, point).
    auto phaseB = [&](int pg) {
        int ep = t & 127;            // e-pair: e = 2*ep, 2*ep+1
        int pq = t >> 7;             // local point 0..3
        int p  = pg * 4 + pq;
        float4 wA = wsb[2 * ep];
        float4 wB = wsb[2 * ep + 1];
        float g0A = 0.f, g0B = 0.f;
        #pragma unroll
        for (int k = 0; k < KNN; k++) {
            float4 hv = hhat4[p][k];
            float vA = fmaf(wA.x, hv.x, fmaf(wA.y, hv.y, fmaf(wA.z, hv.z, wA.w)));
            float vB = fmaf(wB.x, hv.x, fmaf(wB.y, hv.y, fmaf(wB.z, hv.z, wB.w)));
            float gA = gelu_t(vA), gB = gelu_t(vB);
            *(unsigned int*)&hh_bf[pg][(16 * pq + k) * SR + 2 * ep] = pkbf(gA, gB);
            if (k == 0) { g0A = gA; g0B = gB; }
        }
        *(unsigned int*)&hh_bf[pg][(16 * pq + 15) * SR + 2 * ep] = pkbf(g0A, g0B);  // dup row
        float4 pv = xb[n0 + p];
        float peA = bw1[2 * ep] + W1[(2 * ep) * 3] * pv.x
                  + W1[(2 * ep) * 3 + 1] * pv.y + W1[(2 * ep) * 3 + 2] * pv.z;
        float peB = bw1[2 * ep + 1] + W1[(2 * ep + 1) * 3] * pv.x
                  + W1[(2 * ep + 1) * 3 + 1] * pv.y + W1[(2 * ep + 1) * 3 + 2] * pv.z;
        *(unsigned int*)&feat_bf[p * SRF + 2 * ep] = pkbf(peA, peB);
    };

    // phase C(pg): A-operands for BOTH of this wave's f-tiles resident in regs;
    // each hh fragment read ONCE per point, feeds the 2 MFMA chains.
    auto phaseC = [&](int pg) {
        bf8 a0[8], a1[8];
        #pragma unroll
        for (int kb = 0; kb < 8; kb++) {
            a0[kb] = ld_bf8(w2b_t + (w * 2 + 0) * 4096 + kb * 512 + lane * 8);
            a1[kb] = ld_bf8(w2b_t + (w * 2 + 1) * 4096 + kb * 512 + lane * 8);
        }
        #pragma unroll 1
        for (int pp = 0; pp < 4; pp++) {
            bf8 hfr[8];
            #pragma unroll
            for (int kb = 0; kb < 8; kb++)
                hfr[kb] = ld_bf8(&hh_bf[pg][(16 * pp + m) * SR + kb * 32 + q * 8]);
            f4 acc0 = {0.f, 0.f, 0.f, 0.f};
            f4 acc1 = {0.f, 0.f, 0.f, 0.f};
            #pragma unroll
            for (int kb = 0; kb < 8; kb++) {
                acc0 = __builtin_amdgcn_mfma_f32_16x16x32_bf16(hfr[kb], a0[kb], acc0, 0, 0, 0);
                acc1 = __builtin_amdgcn_mfma_f32_16x16x32_bf16(hfr[kb], a1[kb], acc1, 0, 0, 0);
            }
            float mx0 = fmaxf(fmaxf(acc0[0], acc0[1]), fmaxf(acc0[2], acc0[3]));
            float mx1 = fmaxf(fmaxf(acc1[0], acc1[1]), fmaxf(acc1[2], acc1[3]));
            mx0 = fmaxf(mx0, __shfl_xor(mx0, 16));
            mx0 = fmaxf(mx0, __shfl_xor(mx0, 32));
            mx1 = fmaxf(mx1, __shfl_xor(mx1, 16));
            mx1 = fmaxf(mx1, __shfl_xor(mx1, 32));
            if (lane < 16) {
                feat_bf[(pg * 4 + pp) * SRF + E + (w * 2 + 0) * 16 + lane] = f2bf(mx0);
                feat_bf[(pg * 4 + pp) * SRF + E + (w * 2 + 1) * 16 + lane] = f2bf(mx1);
            }
        }
    };

    if (t < P * KNN) {   // phase A: gather + BN2a affine (120 threads, all 8 points)
        int p = t / KNN, k = t % KNN;
        int j = idx[(i0 + p) * KNN + k];
        float4 pj = xb[j];
        float4 pn = xb[n0 + p];
        float4 h;
        h.x = ab[0] * (pj.x - pn.x) + ab[3];
        h.y = ab[1] * (pj.y - pn.y) + ab[4];
        h.z = ab[2] * (pj.z - pn.z) + ab[5];
        h.w = 0.f;
        hhat4[p][k] = h;
    }
    __syncthreads();

    phaseB(0);
    __syncthreads();

    // merged region: B1 (VALU) and C0 (MFMA) have no mutual deps --
    // B1 writes hh[1] + feat rows 4-7 cols<E; C0 reads hh[0], writes
    // feat rows 0-3 cols>=E.  Waves proceed independently -> overlap.
    phaseB(1);
    phaseC(0);
    __syncthreads();

    phaseC(1);
    __syncthreads();

    {   // phase D: wave w -> o-tiles {2w, 2w+1}; cols = 8 points (m&7)
        bf8 fb[16];
        #pragma unroll
        for (int kb = 0; kb < 16; kb++)
            fb[kb] = ld_bf8(&feat_bf[(m & 7) * SRF + kb * 32 + q * 8]);
        #pragma unroll
        for (int o2 = 0; o2 < 2; o2++) {
            int ot = w * 2 + o2;
            f4 acc = {0.f, 0.f, 0.f, 0.f};
            #pragma unroll
            for (int kb = 0; kb < 16; kb++) {
                bf8 a = ld_bf8(wf_t + ot * 8192 + kb * 512 + lane * 8);
                acc = __builtin_amdgcn_mfma_f32_16x16x32_bf16(a, fb[kb], acc, 0, 0, 0);
            }
            if (m < P) {   // col = m = point; row = ot*16 + 4q + reg
                int o0 = ot * 16 + 4 * q;
                out[(b * E + o0 + 0) * N + n0 + m] = acc[0] + bfv[o0 + 0];
                out[(b * E + o0 + 1) * N + n0 + m] = acc[1] + bfv[o0 + 1];
                out[(b * E + o0 + 2) * N + n0 + m] = acc[2] + bfv[o0 + 2];
                out[(b * E + o0 + 3) * N + n0 + m] = acc[3] + bfv[o0 + 3];
            }
        }
    }
}

extern "C" void kernel_launch(void* const* d_in, const int* in_sizes, int n_in,
                              void* d_out, int out_size, void* d_ws, size_t ws_size,
                              hipStream_t stream) {
    (void)in_sizes; (void)n_in; (void)out_size; (void)ws_size;
    const float* x   = (const float*)d_in[0];
    const float* g1  = (const float*)d_in[1];
    const float* b1  = (const float*)d_in[2];
    const float* W1  = (const float*)d_in[3];
    const float* bw1 = (const float*)d_in[4];
    const float* g2a = (const float*)d_in[5];
    const float* b2a = (const float*)d_in[6];
    const float* W2a = (const float*)d_in[7];
    const float* g2b = (const float*)d_in[8];
    const float* b2b = (const float*)d_in[9];
    const float* W2b = (const float*)d_in[10];
    const float* Wf  = (const float*)d_in[11];
    const float* bfv = (const float*)d_in[12];
    float* out = (float*)d_out;

    char* ws = (char*)d_ws;
    size_t off = 0;
    auto alloc = [&](size_t bytes) { size_t o = off; off = (off + bytes + 255) & ~(size_t)255; return o; };
    float4* xn4           = (float4*)(ws + alloc(sizeof(float4) * BN_));
    unsigned short* idx   = (unsigned short*)(ws + alloc(sizeof(unsigned short) * BN_ * KNN));
    float* bn1            = (float*)(ws + alloc(sizeof(float) * 8));
    float* S9             = (float*)(ws + alloc(sizeof(float) * 64 * 9));
    float* ab             = (float*)(ws + alloc(sizeof(float) * 8));
    float4* wsb           = (float4*)(ws + alloc(sizeof(float4) * E));
    unsigned short* w2bt  = (unsigned short*)(ws + alloc(sizeof(unsigned short) * E * E));
    unsigned short* wft   = (unsigned short*)(ws + alloc(sizeof(unsigned short) * E * 2 * E));

    bn1_stats<<<C + 1, 256, 0, stream>>>(x, bn1, S9);
    compute_xn_cvt<<<BN_ / 256 + (8192 + 16384) / 256, 256, 0, stream>>>(
        x, g1, b1, bn1, xn4, W2b, Wf, w2bt, wft);
    knn_kernel<<<BN_ / 4, 256, 0, stream>>>(xn4, idx, S9);
    finalize_stats<<<1, 256, 0, stream>>>(S9, g2a, b2a, W2a, g2b, b2b, ab, wsb);
    fused_final<<<BN_ / P, 512, 0, stream>>>(xn4, idx, ab, wsb, w2bt, W1, bw1, wft, bfv, out);
}